// Round 11
// baseline (227.701 us; speedup 1.0000x reference)
//
#include <hip/hip_runtime.h>
#include <math.h>

#define NTH 512

typedef __attribute__((ext_vector_type(8))) short short8;
typedef __attribute__((ext_vector_type(4))) float f32x4;
typedef unsigned short ushort;
typedef unsigned int uint;
typedef unsigned long long u64;

#define MFMA16(a, b, c) __builtin_amdgcn_mfma_f32_16x16x32_bf16(a, b, c, 0, 0, 0)

// fp32 -> bf16 round-to-nearest-even
__device__ __forceinline__ ushort f2bf(float f) {
  uint u = __float_as_uint(f);
  u = (u + 0x7FFFu + ((u >> 16) & 1u)) >> 16;
  return (ushort)u;
}

// Flat-index LDS XOR-swizzle for A-operand tiles (write & read same (idx,sh)).
__device__ __forceinline__ int swz(int idx, int sh) {
  return idx ^ (((idx >> sh) & 7) << 3);
}

__device__ __forceinline__ float wsum(float v) {
#pragma unroll
  for (int off = 32; off > 0; off >>= 1) v += __shfl_xor(v, off, 64);
  return v;
}

// inline-asm global load (1 KB/wave: 16B per lane). Compiler cannot see the
// VMEM op -> no auto vmcnt(0); completion is gated ONLY by our counted waits.
__device__ __forceinline__ void gload16(short8& dst, const ushort* g) {
  u64 ga = (u64)g;
  asm volatile("global_load_dwordx4 %0, %1, off" : "=v"(dst) : "v"(ga));
}

// counted vmcnt wait; rem_out = loads still outstanding that we allow
__device__ __forceinline__ void vmw(int rem_out) {
  if (rem_out >= 7) asm volatile("s_waitcnt vmcnt(7)" ::: "memory");
  else if (rem_out == 6) asm volatile("s_waitcnt vmcnt(6)" ::: "memory");
  else if (rem_out == 5) asm volatile("s_waitcnt vmcnt(5)" ::: "memory");
  else if (rem_out == 4) asm volatile("s_waitcnt vmcnt(4)" ::: "memory");
  else if (rem_out == 3) asm volatile("s_waitcnt vmcnt(3)" ::: "memory");
  else if (rem_out == 2) asm volatile("s_waitcnt vmcnt(2)" ::: "memory");
  else if (rem_out == 1) asm volatile("s_waitcnt vmcnt(1)" ::: "memory");
  else asm volatile("s_waitcnt vmcnt(0)" ::: "memory");
}

// ---- weight streams in d_ws (bf16, per-wave consumption order) ----------
// chunk (1KB = 512 ushorts) = B-fragments for (tile, kc, ks):
//   [w][kc][i][ks][lane=kg*16+col][j]  (tile = wv + 8*i, k = kc*128+ks*32+kg*8+j)
#define S_CONV2 0        // 16 tiles, K=768 (conv2 re-laid: k=t*256+e)
#define S_TREND 196608   // 16 tiles, K=256
#define S_SEASON 262144  // 16 tiles, K=256
#define S_QKV 327680     // 4 layers x 48 tiles, K=256
#define S_AOW 1114112    // 4 x 16 tiles, K=256
#define S_F1 1376256     // 4 x 64 tiles, K=256
#define S_F2 2424832     // 4 x 16 tiles, K=1024
#define WTOT 3473408

template <int MY, int NCH>
__device__ __forceinline__ void dec(int idx, int& row, int& k) {
  int pos = idx & 511, lane = pos >> 3, j = pos & 7;
  int kg = lane >> 4, col = lane & 15;
  int chunk = idx >> 9, ks = chunk & 3, t2 = chunk >> 2;
  int w = t2 / (MY * NCH), r2 = t2 - w * (MY * NCH);
  int kc = r2 / MY, ii = r2 - kc * MY;
  row = (w + 8 * ii) * 16 + col;
  k = kc * 128 + ks * 32 + kg * 8 + j;
}

__global__ void k_cvt(const float* __restrict__ c2w, const float* __restrict__ tw,
                      const float* __restrict__ sw, const float* __restrict__ aiw,
                      const float* __restrict__ aow, const float* __restrict__ f1w,
                      const float* __restrict__ f2w, ushort* __restrict__ ws) {
  for (int i = blockIdx.x * blockDim.x + threadIdx.x; i < WTOT;
       i += gridDim.x * blockDim.x) {
    float v; int row, k;
    if (i < S_TREND) {
      dec<2, 6>(i, row, k);
      int t = k >> 8, e = k & 255;
      v = c2w[row * 768 + e * 3 + t];
    } else if (i < S_SEASON) {
      dec<2, 2>(i - S_TREND, row, k); v = tw[row * 256 + k];
    } else if (i < S_QKV) {
      dec<2, 2>(i - S_SEASON, row, k); v = sw[row * 256 + k];
    } else if (i < S_AOW) {
      int r = i - S_QKV; int l = r / 196608; r -= l * 196608;
      dec<6, 2>(r, row, k); v = aiw[(size_t)l * 196608 + row * 256 + k];
    } else if (i < S_F1) {
      int r = i - S_AOW; int l = r >> 16; r &= 65535;
      dec<2, 2>(r, row, k); v = aow[l * 65536 + row * 256 + k];
    } else if (i < S_F2) {
      int r = i - S_F1; int l = r >> 18; r &= 262143;
      dec<8, 2>(r, row, k); v = f1w[l * 262144 + row * 256 + k];
    } else {
      int r = i - S_F2; int l = r >> 18; r &= 262143;
      dec<2, 8>(r, row, k); v = f2w[l * 262144 + row * 1024 + k];
    }
    ws[i] = f2bf(v);
  }
}

// ---- MFMA GEMM with register-ring async B streaming ---------------------
// 8-deep ring of short8 (32 VGPRs, 8 KB/wave in flight). Per step:
// counted vmcnt wait -> sched_barrier -> 2 MFMA on slot -> issue refill of
// that slot. AITER pattern: vmcnt is never drained to 0 in steady state.
// R10's LDS-ring variant serialized at ~640 cy/chunk (global_load_lds DMA
// per-wave serialization); register loads pipeline properly.
#define M_F32 0
#define M_F32RELU 1
#define M_SINADD 2
#define M_BF16RELU 4
#define M_QKV 5

template <int KDIM, int NTILES, int MODE, int ASH, int OSH>
__device__ __forceinline__ void gemm20(const ushort* __restrict__ A, int lda,
                                       const ushort* __restrict__ Wst,
                                       const float* __restrict__ bias,
                                       float* __restrict__ outf,
                                       ushort* __restrict__ outb, int ostride,
                                       ushort* __restrict__ vt, int tid) {
  constexpr int NCH = KDIM / 128, MY = NTILES / 8, C = MY * NCH * 4;
  constexpr int R = 8;
  const int lane = tid & 63, wv = tid >> 6, col = lane & 15, kg = lane >> 4;
  const int r0c = col, r1c = (16 + col > 19) ? 19 : (16 + col);
  const ushort* ws0 = Wst + (size_t)wv * C * 512 + lane * 8;

  // bias pre-load + drain (keeps manual vmcnt counts stream-only)
  float bv[MY];
#pragma unroll
  for (int i = 0; i < MY; ++i) bv[i] = bias[(wv + 8 * i) * 16 + col];
  asm volatile("s_waitcnt vmcnt(0)" ::: "memory");

  // prologue: fill the 8-slot register ring
  short8 rg[R];
#pragma unroll
  for (int r = 0; r < R; ++r) gload16(rg[r], ws0 + r * 512);

  f32x4 acc[MY][2];
#pragma unroll
  for (int i = 0; i < MY; ++i) {
    acc[i][0] = {bv[i], bv[i], bv[i], bv[i]};
    acc[i][1] = {bv[i], bv[i], bv[i], bv[i]};
  }

  short8 af0[4], af1[4];
#pragma unroll
  for (int c = 0; c < C; ++c) {
    const int kc = c / (MY * 4), rem = c - kc * (MY * 4);
    const int i = rem >> 2, ks = rem & 3;
    if (rem == 0) {
#pragma unroll
      for (int s = 0; s < 4; ++s) {
        const int k0 = kc * 128 + s * 32 + kg * 8;
        af0[s] = *(const short8*)(A + swz(r0c * lda + k0, ASH));
        af1[s] = *(const short8*)(A + swz(r1c * lda + k0, ASH));
      }
    }
    vmw(C - 1 - c);  // constant after unroll; slot c's data is now resident
    __builtin_amdgcn_sched_barrier(0);
    acc[i][0] = MFMA16(af0[ks], rg[c & 7], acc[i][0]);
    acc[i][1] = MFMA16(af1[ks], rg[c & 7], acc[i][1]);
    if (c + R < C) gload16(rg[c & 7], ws0 + (c + R) * 512);
  }

#pragma unroll
  for (int i = 0; i < MY; ++i) {
    const int og = (wv + 8 * i) * 16 + col;
#pragma unroll
    for (int mt = 0; mt < 2; ++mt) {
#pragma unroll
      for (int j = 0; j < 4; ++j) {
        const int row = mt * 16 + kg * 4 + j;
        if (row < 20) {
          float v = acc[i][mt][j];
          if (MODE == M_F32) outf[row * ostride + og] = v;
          if (MODE == M_F32RELU) outf[row * ostride + og] = fmaxf(v, 0.f);
          if (MODE == M_SINADD) outf[row * ostride + og] += sinf(v);
          if (MODE == M_BF16RELU)
            outb[swz(row * ostride + og, OSH)] = f2bf(fmaxf(v, 0.f));
          if (MODE == M_QKV) {
            ushort bvu = f2bf(v);
            outb[swz(row * ostride + og, OSH)] = bvu;
            if (og >= 512) {  // V -> transposed copy vt[h][dh][token]
              int hh = (og - 512) >> 5, dh = (og - 512) & 31;
              vt[swz(hh * 1024 + dh * 32 + row, 5)] = bvu;
            }
          }
        }
      }
    }
  }
}

// in-place LayerNorm over 20 rows of H; optional residual add; bf16 mirror hb
__device__ __forceinline__ void ln20(float (*H)[256], ushort* __restrict__ hb,
                                     const float* __restrict__ add,
                                     const float* __restrict__ g,
                                     const float* __restrict__ bt, int tid) {
  const int lane = tid & 63;
  const int wv = tid >> 6;
  const int d0 = lane * 4;
  for (int r = wv; r < 20; r += 8) {
    float xv[4];
#pragma unroll
    for (int j = 0; j < 4; ++j) {
      xv[j] = H[r][d0 + j];
      if (add) xv[j] += add[r * 256 + d0 + j];
    }
    float m = wsum(xv[0] + xv[1] + xv[2] + xv[3]) * (1.f / 256.f);
    float c0 = xv[0] - m, c1 = xv[1] - m, c2 = xv[2] - m, c3 = xv[3] - m;
    float var = wsum(c0 * c0 + c1 * c1 + c2 * c2 + c3 * c3) * (1.f / 256.f);
    float inv = rsqrtf(var + 1e-5f);
#pragma unroll
    for (int j = 0; j < 4; ++j) {
      float cj = (j == 0 ? c0 : j == 1 ? c1 : j == 2 ? c2 : c3);
      float o = cj * inv * g[d0 + j] + bt[d0 + j];
      H[r][d0 + j] = o;
      hb[swz(r * 256 + d0 + j, 8)] = f2bf(o);
    }
  }
}

__global__ __launch_bounds__(NTH, 2) void aai_main(
    const float* __restrict__ x, const float* __restrict__ c1w,
    const float* __restrict__ c1b, const float* __restrict__ c2b,
    const float* __restrict__ lnfg, const float* __restrict__ lnfb,
    const float* __restrict__ tb, const float* __restrict__ sb,
    const float* __restrict__ aib, const float* __restrict__ aob_b,
    const float* __restrict__ l1g, const float* __restrict__ l1b,
    const float* __restrict__ f1b, const float* __restrict__ f2b,
    const float* __restrict__ l2g, const float* __restrict__ l2b,
    const float* __restrict__ fcw, const float* __restrict__ fcb,
    const ushort* __restrict__ ws, float* __restrict__ out) {
  __shared__ float xs[24][16];
  __shared__ float h[20][256];
  __shared__ float bb[20][256];          // also overlays attn scores (f32)
  __shared__ __align__(16) ushort hb[20 * 256];
  __shared__ __align__(16) ushort qkvb[20 * 768];
  __shared__ __align__(16) ushort big[20480];  // c1/ffb | {aob,P,vT}

  const int tid = threadIdx.x;
  const int b = blockIdx.x;
  const int lane = tid & 63;
  const int wv = tid >> 6;
  const int col = lane & 15;
  const int kg = lane >> 4;
  const int r1c = (16 + col > 19) ? 19 : (16 + col);

  ushort* c1u = big;           // [22][256]  (swz sh=8)
  ushort* ffb = big;           // [20][1024] (swz sh=10)
  ushort* aob = big;           // [20][256]  (swz sh=8)
  ushort* Pb = big + 5120;     // [8][20][32] (swz sh=5)
  ushort* vT = big + 10240;    // [8][32][32] (swz sh=5)
  float* scores = &bb[0][0];   // [8][20][20] overlay (bb dead in attn phase)

  // ---- stage x tail (t = 3977..3999, row 23 = 0)
  for (int i = tid; i < 24 * 16; i += NTH) {
    int r = i >> 4, c = i & 15;
    xs[r][c] = (r < 23) ? x[((size_t)b * 4000 + 3977 + r) * 16 + c] : 0.f;
  }
  __syncthreads();

  // ---- conv1 + ReLU -> c1 bf16 (rows t=3979..3999, row 21 = t=4000 = 0)
  if (tid < 256) {
    const int d = tid;
    const float* wr = c1w + d * 48;
    float acc[21];
    const float bv = c1b[d];
#pragma unroll
    for (int r = 0; r < 21; ++r) acc[r] = bv;
    for (int c = 0; c < 16; ++c) {
      float xv[23];
#pragma unroll
      for (int i = 0; i < 23; ++i) xv[i] = xs[i + 1][c];
      float w0 = wr[c * 3], w1 = wr[c * 3 + 1], w2 = wr[c * 3 + 2];
#pragma unroll
      for (int r = 0; r < 21; ++r)
        acc[r] += xv[r] * w0 + xv[r + 1] * w1 + xv[r + 2] * w2;
    }
#pragma unroll
    for (int r = 0; r < 21; ++r)
      c1u[swz(r * 256 + d, 8)] = f2bf(fmaxf(acc[r], 0.f));
    c1u[swz(21 * 256 + d, 8)] = 0;
  }
  __syncthreads();

  // ---- conv2 + ReLU -> h fp32 (GEMM: A[r][k]=c1_flat[r*256+k], K=768)
  gemm20<768, 16, M_F32RELU, 8, 8>(c1u, 256, ws + S_CONV2, c2b, &h[0][0],
                                   nullptr, 256, nullptr, tid);
  __syncthreads();

  // ---- LayerNorm_f
  ln20(h, hb, nullptr, lnfg, lnfb, tid);
  __syncthreads();

  // ---- trend -> bb ; season -> bb += sin(.)
  gemm20<256, 16, M_F32, 8, 8>(hb, 256, ws + S_TREND, tb, &bb[0][0], nullptr,
                               256, nullptr, tid);
  __syncthreads();
  gemm20<256, 16, M_SINADD, 8, 8>(hb, 256, ws + S_SEASON, sb, &bb[0][0],
                                  nullptr, 256, nullptr, tid);
  __syncthreads();
  for (int i = tid; i < 20 * 256; i += NTH) {
    float v = (&h[0][0])[i] + (&bb[0][0])[i];
    (&h[0][0])[i] = v;
    hb[swz(i, 8)] = f2bf(v);
  }
  __syncthreads();

  // ---- encoder layers
  for (int l = 0; l < 4; ++l) {
    // qkv projection: 48 tiles in one call (MY=6) -> qkvb bf16 + vT
    gemm20<256, 48, M_QKV, 8, 8>(hb, 256, ws + S_QKV + l * 196608,
                                 aib + l * 768, nullptr, qkvb, 768, vT, tid);
    // vT pad tokens 20..31 never written by the epilogue -> zero (layer-0 LDS
    // garbage there can be NaN/Inf bf16 and 0*Inf = NaN in the PV MFMA).
    for (int i = tid; i < 8 * 32 * 12; i += NTH) {
      int hh = i / 384, r = i - hh * 384;
      int dh = r / 12, tk = 20 + (r - dh * 12);
      vT[swz(hh * 1024 + dh * 32 + tk, 5)] = 0;
    }
    __syncthreads();

    // scores = Q.K^T / sqrt(32), one head per wave (8 waves = 8 heads)
    {
      const int hh = wv;
      short8 aq[2], bk[2];
      aq[0] = *(const short8*)(qkvb + swz(col * 768 + hh * 32 + kg * 8, 8));
      aq[1] = *(const short8*)(qkvb + swz(r1c * 768 + hh * 32 + kg * 8, 8));
      bk[0] = *(const short8*)(qkvb + swz(col * 768 + 256 + hh * 32 + kg * 8, 8));
      bk[1] = *(const short8*)(qkvb + swz(r1c * 768 + 256 + hh * 32 + kg * 8, 8));
      f32x4 dqk[2][2];
#pragma unroll
      for (int mt = 0; mt < 2; ++mt)
#pragma unroll
        for (int nt = 0; nt < 2; ++nt) {
          dqk[mt][nt] = {0.f, 0.f, 0.f, 0.f};
          dqk[mt][nt] = MFMA16(aq[mt], bk[nt], dqk[mt][nt]);
        }
#pragma unroll
      for (int mt = 0; mt < 2; ++mt)
#pragma unroll
        for (int nt = 0; nt < 2; ++nt)
#pragma unroll
          for (int j = 0; j < 4; ++j) {
            int row = mt * 16 + kg * 4 + j, kj = nt * 16 + col;
            if (row < 20 && kj < 20)
              scores[hh * 400 + row * 20 + kj] =
                  dqk[mt][nt][j] * 0.17677669529663687f;
          }
    }
    __syncthreads();

    // softmax rows -> P bf16 [8][20][32], zero-padded to K=32
    if (tid < 160) {
      const int hh = tid / 20, q = tid - hh * 20;
      const float* row = scores + hh * 400 + q * 20;
      float m = row[0];
#pragma unroll
      for (int j = 1; j < 20; ++j) m = fmaxf(m, row[j]);
      float e[20], s = 0.f;
#pragma unroll
      for (int j = 0; j < 20; ++j) { e[j] = __expf(row[j] - m); s += e[j]; }
      float inv = 1.f / s;
#pragma unroll
      for (int j = 0; j < 20; ++j)
        Pb[swz(hh * 640 + q * 32 + j, 5)] = f2bf(e[j] * inv);
#pragma unroll
      for (int j = 20; j < 32; ++j) Pb[swz(hh * 640 + q * 32 + j, 5)] = 0;
    }
    __syncthreads();

    // O = P @ V per head (one head per wave) via MFMA (K=32) -> aob bf16
    {
      const int hh = wv;
      short8 ap[2], bvv[2];
      ap[0] = *(const short8*)(Pb + swz(hh * 640 + col * 32 + kg * 8, 5));
      ap[1] = *(const short8*)(Pb + swz(hh * 640 + r1c * 32 + kg * 8, 5));
      bvv[0] = *(const short8*)(vT + swz(hh * 1024 + col * 32 + kg * 8, 5));
      bvv[1] = *(const short8*)(vT + swz(hh * 1024 + (16 + col) * 32 + kg * 8, 5));
      f32x4 dav[2][2];
#pragma unroll
      for (int mt = 0; mt < 2; ++mt)
#pragma unroll
        for (int nt = 0; nt < 2; ++nt) {
          dav[mt][nt] = {0.f, 0.f, 0.f, 0.f};
          dav[mt][nt] = MFMA16(ap[mt], bvv[nt], dav[mt][nt]);
        }
#pragma unroll
      for (int mt = 0; mt < 2; ++mt)
#pragma unroll
        for (int nt = 0; nt < 2; ++nt)
#pragma unroll
          for (int j = 0; j < 4; ++j) {
            int row = mt * 16 + kg * 4 + j, dc = nt * 16 + col;
            if (row < 20)
              aob[swz(row * 256 + hh * 32 + dc, 8)] = f2bf(dav[mt][nt][j]);
          }
    }
    __syncthreads();

    // out projection -> bb fp32 (scores region dead by now)
    gemm20<256, 16, M_F32, 8, 8>(aob, 256, ws + S_AOW + l * 65536,
                                 aob_b + l * 256, &bb[0][0], nullptr, 256,
                                 nullptr, tid);
    __syncthreads();
    // h = LN1(h + proj)
    ln20(h, hb, &bb[0][0], l1g + l * 256, l1b + l * 256, tid);
    __syncthreads();
    // ff1 + ReLU -> ffb bf16 [20][1024] (one call, MY=8)
    gemm20<256, 64, M_BF16RELU, 8, 10>(hb, 256, ws + S_F1 + l * 262144,
                                       f1b + l * 1024, nullptr, ffb, 1024,
                                       nullptr, tid);
    __syncthreads();
    // ff2 -> bb fp32
    gemm20<1024, 16, M_F32, 10, 8>(ffb, 1024, ws + S_F2 + l * 262144,
                                   f2b + l * 256, &bb[0][0], nullptr, 256,
                                   nullptr, tid);
    __syncthreads();
    // h = LN2(h + ff)
    ln20(h, hb, &bb[0][0], l2g + l * 256, l2b + l * 256, tid);
    __syncthreads();
  }

  // ---- final fc on last token (row 19), fp32: 8 waves x 2 outputs
  for (int o = wv; o < 16; o += 8) {
    float4 hv = *(const float4*)(&h[19][lane * 4]);
    float4 w4 = *(const float4*)(&fcw[o * 256 + lane * 4]);
    float s = hv.x * w4.x + hv.y * w4.y + hv.z * w4.z + hv.w * w4.w;
    s = wsum(s);
    if (lane == 0) out[b * 16 + o] = s + fcb[o];
  }
}

extern "C" void kernel_launch(void* const* d_in, const int* in_sizes, int n_in,
                              void* d_out, int out_size, void* d_ws, size_t ws_size,
                              hipStream_t stream) {
  const float* x    = (const float*)d_in[0];
  const float* c1w  = (const float*)d_in[1];
  const float* c1b  = (const float*)d_in[2];
  const float* c2w  = (const float*)d_in[3];
  const float* c2b  = (const float*)d_in[4];
  const float* lnfg = (const float*)d_in[5];
  const float* lnfb = (const float*)d_in[6];
  const float* tw   = (const float*)d_in[7];
  const float* tb   = (const float*)d_in[8];
  const float* sw   = (const float*)d_in[9];
  const float* sb   = (const float*)d_in[10];
  const float* aiw  = (const float*)d_in[11];
  const float* aib  = (const float*)d_in[12];
  const float* aow  = (const float*)d_in[13];
  const float* aobb = (const float*)d_in[14];
  const float* l1g  = (const float*)d_in[15];
  const float* l1b  = (const float*)d_in[16];
  const float* f1w  = (const float*)d_in[17];
  const float* f1b  = (const float*)d_in[18];
  const float* f2w  = (const float*)d_in[19];
  const float* f2b  = (const float*)d_in[20];
  const float* l2g  = (const float*)d_in[21];
  const float* l2b  = (const float*)d_in[22];
  const float* fcw  = (const float*)d_in[23];
  const float* fcb  = (const float*)d_in[24];
  float* out = (float*)d_out;
  ushort* ws = (ushort*)d_ws;

  k_cvt<<<4096, 256, 0, stream>>>(c2w, tw, sw, aiw, aow, f1w, f2w, ws);
  aai_main<<<32, NTH, 0, stream>>>(x, c1w, c1b, c2b, lnfg, lnfb, tb, sb, aib,
                                   aobb, l1g, l1b, f1b, f2b, l2g, l2b, fcw,
                                   fcb, ws, out);
}

// Round 12
// 154.781 us; speedup vs baseline: 1.4711x; 1.4711x over previous
//
#include <hip/hip_runtime.h>
#include <math.h>

typedef __attribute__((ext_vector_type(8))) short short8;
typedef __attribute__((ext_vector_type(4))) short short4v;
typedef __attribute__((ext_vector_type(4))) float f32x4;
typedef unsigned short ushort;
typedef unsigned int uint;
typedef unsigned long long u64;

#define MFMA16(a, b, c) __builtin_amdgcn_mfma_f32_16x16x32_bf16(a, b, c, 0, 0, 0)

__device__ __forceinline__ ushort f2bf(float f) {
  uint u = __float_as_uint(f);
  u = (u + 0x7FFFu + ((u >> 16) & 1u)) >> 16;
  return (ushort)u;
}
__device__ __forceinline__ int swz(int idx, int sh) {
  return idx ^ (((idx >> sh) & 7) << 3);
}
__device__ __forceinline__ float wsum(float v) {
#pragma unroll
  for (int off = 32; off > 0; off >>= 1) v += __shfl_xor(v, off, 64);
  return v;
}
__device__ __forceinline__ void gload16(short8& dst, const ushort* g) {
  u64 ga = (u64)g;
  asm volatile("global_load_dwordx4 %0, %1, off" : "=v"(dst) : "v"(ga));
}
__device__ __forceinline__ void vmw(int n) {
  if (n >= 7) asm volatile("s_waitcnt vmcnt(7)" ::: "memory");
  else if (n == 6) asm volatile("s_waitcnt vmcnt(6)" ::: "memory");
  else if (n == 5) asm volatile("s_waitcnt vmcnt(5)" ::: "memory");
  else if (n == 4) asm volatile("s_waitcnt vmcnt(4)" ::: "memory");
  else if (n == 3) asm volatile("s_waitcnt vmcnt(3)" ::: "memory");
  else if (n == 2) asm volatile("s_waitcnt vmcnt(2)" ::: "memory");
  else if (n == 1) asm volatile("s_waitcnt vmcnt(1)" ::: "memory");
  else asm volatile("s_waitcnt vmcnt(0)" ::: "memory");
}

// ---- weight stream layout (tile-major): chunk(1KB) = (tile, kc, ks) ------
#define S_CONV2 0
#define S_TREND 196608
#define S_SEASON 262144
#define S_QKV 327680
#define S_AOW 1114112
#define S_F1 1376256
#define S_F2 2424832
#define WTOT 3473408
// activation buffers (ushort offsets in d_ws)
#define O_C1G 3473408   // bf16 [32][5632]
#define O_C2O 3653632   // f32 [32][5120]
#define O_G0 3981312    // f32 [32][5120]
#define O_G1 4308992    // f32 [32][5120]
#define O_PEND 4636672  // f32 [32][5120]
#define O_QKV 4964352   // bf16 [32][15360]
#define O_FFB 5455872   // bf16 [32][20480]

template <int NCH>
__device__ __forceinline__ void dec2(int idx, int& row, int& k) {
  int pos = idx & 511, lane = pos >> 3, j = pos & 7;
  int kg = lane >> 4, col = lane & 15;
  int chunk = idx >> 9;
  int tile = chunk / (NCH * 4), r = chunk - tile * (NCH * 4);
  int kc = r >> 2, ks = r & 3;
  row = tile * 16 + col;
  k = kc * 128 + ks * 32 + kg * 8 + j;
}

__global__ void k_cvt(const float* __restrict__ c2w, const float* __restrict__ tw,
                      const float* __restrict__ sw, const float* __restrict__ aiw,
                      const float* __restrict__ aow, const float* __restrict__ f1w,
                      const float* __restrict__ f2w, ushort* __restrict__ ws) {
  for (int i = blockIdx.x * blockDim.x + threadIdx.x; i < WTOT;
       i += gridDim.x * blockDim.x) {
    float v; int row, k;
    if (i < S_TREND) {
      dec2<6>(i, row, k);
      int t = k >> 8, e = k & 255;
      v = c2w[row * 768 + e * 3 + t];
    } else if (i < S_SEASON) { dec2<2>(i - S_TREND, row, k); v = tw[row * 256 + k]; }
    else if (i < S_QKV) { dec2<2>(i - S_SEASON, row, k); v = sw[row * 256 + k]; }
    else if (i < S_AOW) {
      int r = i - S_QKV; int l = r / 196608; r -= l * 196608;
      dec2<2>(r, row, k); v = aiw[(size_t)l * 196608 + row * 256 + k];
    } else if (i < S_F1) {
      int r = i - S_AOW; int l = r >> 16; r &= 65535;
      dec2<2>(r, row, k); v = aow[l * 65536 + row * 256 + k];
    } else if (i < S_F2) {
      int r = i - S_F1; int l = r >> 18; r &= 262143;
      dec2<2>(r, row, k); v = f1w[l * 262144 + row * 256 + k];
    } else {
      int r = i - S_F2; int l = r >> 18; r &= 262143;
      dec2<8>(r, row, k); v = f2w[l * 262144 + row * 1024 + k];
    }
    ws[i] = f2bf(v);
  }
}

// ---- generic ring GEMM core: wave streams MY consecutive tiles ----------
template <int NCH, int MY, int ASH>
__device__ __forceinline__ void ring_gemm(const ushort* __restrict__ A, int lda,
                                          const ushort* __restrict__ ws0,
                                          int lane, f32x4 (&acc)[MY][2]) {
  constexpr int C = MY * NCH * 4;
  constexpr int R = (C < 8) ? C : 8;
  const int col = lane & 15, kg = lane >> 4;
  const int r1c = (16 + col > 19) ? 19 : (16 + col);
  short8 rg[R];
#pragma unroll
  for (int r = 0; r < R; ++r) gload16(rg[r], ws0 + r * 512);
  short8 af0[4], af1[4];
#pragma unroll
  for (int c = 0; c < C; ++c) {
    const int i = c / (NCH * 4), r = c - i * (NCH * 4);
    const int kc = r >> 2, ks = r & 3;
    if (ks == 0) {
#pragma unroll
      for (int s = 0; s < 4; ++s) {
        const int k0 = kc * 128 + s * 32 + kg * 8;
        af0[s] = *(const short8*)(A + swz(col * lda + k0, ASH));
        af1[s] = *(const short8*)(A + swz(r1c * lda + k0, ASH));
      }
    }
    int allow = C - 1 - c; if (allow > R - 1) allow = R - 1;
    vmw(allow);
    __builtin_amdgcn_sched_barrier(0);
    acc[i][0] = MFMA16(af0[ks], rg[c % R], acc[i][0]);
    acc[i][1] = MFMA16(af1[ks], rg[c % R], acc[i][1]);
    if (c + R < C) gload16(rg[c % R], ws0 + (c + R) * 512);
  }
}

// ---- A staging helpers (256 threads) ------------------------------------
__device__ __forceinline__ void stage_b16(const ushort* __restrict__ g, ushort* hb,
                                          int n, int sh, int tid) {
  for (int i = tid * 8; i < n; i += 2048) {
    short8 v = *(const short8*)(g + i);
    *(short8*)(hb + swz(i, sh)) = v;
  }
}
__device__ __forceinline__ void stage_f32(const float* __restrict__ g, ushort* hb, int tid) {
  for (int i = tid * 8; i < 5120; i += 2048) {
    float4 a = *(const float4*)(g + i);
    float4 b = *(const float4*)(g + i + 4);
    short8 t;
    t[0] = f2bf(a.x); t[1] = f2bf(a.y); t[2] = f2bf(a.z); t[3] = f2bf(a.w);
    t[4] = f2bf(b.x); t[5] = f2bf(b.y); t[6] = f2bf(b.z); t[7] = f2bf(b.w);
    *(short8*)(hb + swz(i, 8)) = t;
  }
}
// LN(g1 [+pend]) -> hb bf16 swz8 ; optional fp32 writeback gout / LDS copy
__device__ __forceinline__ void stage_ln(const float* __restrict__ g1,
                                         const float* __restrict__ pend,
                                         const float* __restrict__ gam,
                                         const float* __restrict__ bet,
                                         ushort* hb, float* __restrict__ gout,
                                         float* f32lds, int tid) {
  const int lane = tid & 63, w = tid >> 6, d0 = lane * 4;
  for (int r = w; r < 20; r += 4) {
    float4 a = *(const float4*)(g1 + r * 256 + d0);
    if (pend) {
      float4 p = *(const float4*)(pend + r * 256 + d0);
      a.x += p.x; a.y += p.y; a.z += p.z; a.w += p.w;
    }
    float m = wsum(a.x + a.y + a.z + a.w) * (1.f / 256.f);
    float c0 = a.x - m, c1 = a.y - m, c2 = a.z - m, c3 = a.w - m;
    float var = wsum(c0 * c0 + c1 * c1 + c2 * c2 + c3 * c3) * (1.f / 256.f);
    float inv = rsqrtf(var + 1e-5f);
    float o0 = c0 * inv * gam[d0] + bet[d0];
    float o1 = c1 * inv * gam[d0 + 1] + bet[d0 + 1];
    float o2 = c2 * inv * gam[d0 + 2] + bet[d0 + 2];
    float o3 = c3 * inv * gam[d0 + 3] + bet[d0 + 3];
    short4v t; t[0] = f2bf(o0); t[1] = f2bf(o1); t[2] = f2bf(o2); t[3] = f2bf(o3);
    *(short4v*)(hb + swz(r * 256 + d0, 8)) = t;
    if (gout) { float4 o = {o0, o1, o2, o3}; *(float4*)(gout + r * 256 + d0) = o; }
    if (f32lds) { float4 o = {o0, o1, o2, o3}; *(float4*)(f32lds + r * 256 + d0) = o; }
  }
}

// ---- phase kernels -------------------------------------------------------
__global__ __launch_bounds__(256) void k_conv1(const float* __restrict__ x,
                                               const float* __restrict__ c1w,
                                               const float* __restrict__ c1b,
                                               ushort* __restrict__ c1g) {
  __shared__ float xs[24][16];
  const int tid = threadIdx.x, b = blockIdx.x;
  for (int i = tid; i < 24 * 16; i += 256) {
    int r = i >> 4, c = i & 15;
    xs[r][c] = (r < 23) ? x[((size_t)b * 4000 + 3977 + r) * 16 + c] : 0.f;
  }
  __syncthreads();
  const int d = tid;
  const float* wr = c1w + d * 48;
  float acc[21];
  const float bv = c1b[d];
#pragma unroll
  for (int r = 0; r < 21; ++r) acc[r] = bv;
  for (int c = 0; c < 16; ++c) {
    float xv[23];
#pragma unroll
    for (int i = 0; i < 23; ++i) xv[i] = xs[i + 1][c];
    float w0 = wr[c * 3], w1 = wr[c * 3 + 1], w2 = wr[c * 3 + 2];
#pragma unroll
    for (int r = 0; r < 21; ++r)
      acc[r] += xv[r] * w0 + xv[r + 1] * w1 + xv[r + 2] * w2;
  }
  ushort* o = c1g + b * 5632;
#pragma unroll
  for (int r = 0; r < 21; ++r) o[r * 256 + d] = f2bf(fmaxf(acc[r], 0.f));
  o[21 * 256 + d] = 0;
}

__global__ __launch_bounds__(256, 2) void k_conv2(const ushort* __restrict__ c1g,
                                                  const ushort* __restrict__ wst,
                                                  const float* __restrict__ c2b,
                                                  float* __restrict__ c2o) {
  __shared__ __align__(16) ushort hb[5632];
  const int tid = threadIdx.x, lane = tid & 63, wv = tid >> 6;
  const int b = blockIdx.x >> 2, slice = blockIdx.x & 3;
  const int col = lane & 15, kg = lane >> 4;
  stage_b16(c1g + b * 5632, hb, 5632, 8, tid);
  const int tile = slice * 4 + wv, og = tile * 16 + col;
  float bv = c2b[og];
  __syncthreads();
  asm volatile("s_waitcnt vmcnt(0)" ::: "memory");
  f32x4 acc[1][2];
  acc[0][0] = {bv, bv, bv, bv}; acc[0][1] = {bv, bv, bv, bv};
  ring_gemm<6, 1, 8>(hb, 256, wst + tile * 12288 + lane * 8, lane, acc);
  float* ob = c2o + b * 5120;
#pragma unroll
  for (int mt = 0; mt < 2; ++mt)
#pragma unroll
    for (int j = 0; j < 4; ++j) {
      int row = mt * 16 + kg * 4 + j;
      if (row < 20) ob[row * 256 + og] = fmaxf(acc[0][mt][j], 0.f);
    }
}

__global__ __launch_bounds__(256, 2) void k_tresea(
    const float* __restrict__ c2o, const ushort* __restrict__ wtr,
    const ushort* __restrict__ wse, const float* __restrict__ lnfg,
    const float* __restrict__ lnfb, const float* __restrict__ tb,
    const float* __restrict__ sb, float* __restrict__ g0) {
  __shared__ __align__(16) ushort hb[5120];
  __shared__ float hf[5120];
  const int tid = threadIdx.x, lane = tid & 63, wv = tid >> 6;
  const int b = blockIdx.x >> 2, slice = blockIdx.x & 3;
  const int col = lane & 15, kg = lane >> 4;
  stage_ln(c2o + b * 5120, nullptr, lnfg, lnfb, hb, nullptr, hf, tid);
  const int tile = slice * 4 + wv, og = tile * 16 + col;
  float bt = tb[og], bs = sb[og];
  __syncthreads();
  asm volatile("s_waitcnt vmcnt(0)" ::: "memory");
  f32x4 at[1][2], as_[1][2];
  at[0][0] = {bt, bt, bt, bt}; at[0][1] = {bt, bt, bt, bt};
  as_[0][0] = {bs, bs, bs, bs}; as_[0][1] = {bs, bs, bs, bs};
  ring_gemm<2, 1, 8>(hb, 256, wtr + tile * 4096 + lane * 8, lane, at);
  ring_gemm<2, 1, 8>(hb, 256, wse + tile * 4096 + lane * 8, lane, as_);
  float* ob = g0 + b * 5120;
#pragma unroll
  for (int mt = 0; mt < 2; ++mt)
#pragma unroll
    for (int j = 0; j < 4; ++j) {
      int row = mt * 16 + kg * 4 + j;
      if (row < 20)
        ob[row * 256 + og] = hf[row * 256 + og] + at[0][mt][j] + sinf(as_[0][mt][j]);
    }
}

// qkv projection; fuse_ln: A = LN2(g_in + pend) (slice0 writes gout fp32)
__global__ __launch_bounds__(256, 2) void k_qkv(
    const float* __restrict__ gin, const float* __restrict__ pend,
    const float* __restrict__ lng, const float* __restrict__ lnb, int fuse_ln,
    float* __restrict__ gout, const ushort* __restrict__ wst,
    const float* __restrict__ bias, ushort* __restrict__ qkvo) {
  __shared__ __align__(16) ushort hb[5120];
  const int tid = threadIdx.x, lane = tid & 63, wv = tid >> 6;
  const int b = blockIdx.x / 12, slice = blockIdx.x % 12;
  const int col = lane & 15, kg = lane >> 4;
  if (fuse_ln)
    stage_ln(gin + b * 5120, pend + b * 5120, lng, lnb, hb,
             (slice == 0) ? (gout + b * 5120) : nullptr, nullptr, tid);
  else
    stage_f32(gin + b * 5120, hb, tid);
  const int tile = slice * 4 + wv, og = tile * 16 + col;
  float bv = bias[og];
  __syncthreads();
  asm volatile("s_waitcnt vmcnt(0)" ::: "memory");
  f32x4 acc[1][2];
  acc[0][0] = {bv, bv, bv, bv}; acc[0][1] = {bv, bv, bv, bv};
  ring_gemm<2, 1, 8>(hb, 256, wst + tile * 4096 + lane * 8, lane, acc);
  ushort* ob = qkvo + b * 15360;
#pragma unroll
  for (int mt = 0; mt < 2; ++mt)
#pragma unroll
    for (int j = 0; j < 4; ++j) {
      int row = mt * 16 + kg * 4 + j;
      if (row < 20) ob[row * 768 + og] = f2bf(acc[0][mt][j]);
    }
}

// attention (redundant per slice) + out-projection slice -> pend
__global__ __launch_bounds__(256, 2) void k_attnaow(
    const ushort* __restrict__ qkvo, const ushort* __restrict__ wst,
    const float* __restrict__ bias, float* __restrict__ pend) {
  __shared__ __align__(16) ushort qb[15360];
  __shared__ __align__(16) ushort vT[8192];
  __shared__ __align__(16) ushort Pb[5120];
  __shared__ __align__(16) ushort aob[5120];
  __shared__ float sc[3200];
  const int tid = threadIdx.x, lane = tid & 63, wv = tid >> 6;
  const int b = blockIdx.x >> 2, slice = blockIdx.x & 3;
  const int col = lane & 15, kg = lane >> 4;
  const int r1c = (16 + col > 19) ? 19 : (16 + col);
  stage_b16(qkvo + b * 15360, qb, 15360, 8, tid);
  __syncthreads();
  for (int i = tid; i < 8192; i += 256) {
    int hh = i >> 10, rem = i & 1023, dh = rem >> 5, tk = rem & 31;
    ushort v = (tk < 20) ? qb[swz(tk * 768 + 512 + hh * 32 + dh, 8)] : (ushort)0;
    vT[swz(i, 5)] = v;
  }
  __syncthreads();
  for (int hh = wv; hh < 8; hh += 4) {
    short8 aq[2], bk[2];
    aq[0] = *(const short8*)(qb + swz(col * 768 + hh * 32 + kg * 8, 8));
    aq[1] = *(const short8*)(qb + swz(r1c * 768 + hh * 32 + kg * 8, 8));
    bk[0] = *(const short8*)(qb + swz(col * 768 + 256 + hh * 32 + kg * 8, 8));
    bk[1] = *(const short8*)(qb + swz(r1c * 768 + 256 + hh * 32 + kg * 8, 8));
    f32x4 d[2][2];
#pragma unroll
    for (int mt = 0; mt < 2; ++mt)
#pragma unroll
      for (int nt = 0; nt < 2; ++nt) {
        d[mt][nt] = {0.f, 0.f, 0.f, 0.f};
        d[mt][nt] = MFMA16(aq[mt], bk[nt], d[mt][nt]);
      }
#pragma unroll
    for (int mt = 0; mt < 2; ++mt)
#pragma unroll
      for (int nt = 0; nt < 2; ++nt)
#pragma unroll
        for (int j = 0; j < 4; ++j) {
          int row = mt * 16 + kg * 4 + j, kj = nt * 16 + col;
          if (row < 20 && kj < 20)
            sc[hh * 400 + row * 20 + kj] = d[mt][nt][j] * 0.17677669529663687f;
        }
  }
  __syncthreads();
  if (tid < 160) {
    const int hh = tid / 20, q = tid - hh * 20;
    const float* row = sc + hh * 400 + q * 20;
    float m = row[0];
#pragma unroll
    for (int j = 1; j < 20; ++j) m = fmaxf(m, row[j]);
    float e[20], s = 0.f;
#pragma unroll
    for (int j = 0; j < 20; ++j) { e[j] = __expf(row[j] - m); s += e[j]; }
    float inv = 1.f / s;
#pragma unroll
    for (int j = 0; j < 20; ++j) Pb[swz(hh * 640 + q * 32 + j, 5)] = f2bf(e[j] * inv);
#pragma unroll
    for (int j = 20; j < 32; ++j) Pb[swz(hh * 640 + q * 32 + j, 5)] = 0;
  }
  __syncthreads();
  for (int hh = wv; hh < 8; hh += 4) {
    short8 ap[2], bvv[2];
    ap[0] = *(const short8*)(Pb + swz(hh * 640 + col * 32 + kg * 8, 5));
    ap[1] = *(const short8*)(Pb + swz(hh * 640 + r1c * 32 + kg * 8, 5));
    bvv[0] = *(const short8*)(vT + swz(hh * 1024 + col * 32 + kg * 8, 5));
    bvv[1] = *(const short8*)(vT + swz(hh * 1024 + (16 + col) * 32 + kg * 8, 5));
    f32x4 d[2][2];
#pragma unroll
    for (int mt = 0; mt < 2; ++mt)
#pragma unroll
      for (int nt = 0; nt < 2; ++nt) {
        d[mt][nt] = {0.f, 0.f, 0.f, 0.f};
        d[mt][nt] = MFMA16(ap[mt], bvv[nt], d[mt][nt]);
      }
#pragma unroll
    for (int mt = 0; mt < 2; ++mt)
#pragma unroll
      for (int nt = 0; nt < 2; ++nt)
#pragma unroll
        for (int j = 0; j < 4; ++j) {
          int row = mt * 16 + kg * 4 + j, dc = nt * 16 + col;
          if (row < 20) aob[swz(row * 256 + hh * 32 + dc, 8)] = f2bf(d[mt][nt][j]);
        }
  }
  __syncthreads();
  const int tile = slice * 4 + wv, og = tile * 16 + col;
  float bv = bias[og];
  asm volatile("s_waitcnt vmcnt(0)" ::: "memory");
  f32x4 acc[1][2];
  acc[0][0] = {bv, bv, bv, bv}; acc[0][1] = {bv, bv, bv, bv};
  ring_gemm<2, 1, 8>(aob, 256, wst + tile * 4096 + lane * 8, lane, acc);
  float* ob = pend + b * 5120;
#pragma unroll
  for (int mt = 0; mt < 2; ++mt)
#pragma unroll
    for (int j = 0; j < 4; ++j) {
      int row = mt * 16 + kg * 4 + j;
      if (row < 20) ob[row * 256 + og] = acc[0][mt][j];
    }
}

// ff1: A = LN1(g0 + pend), slice0 writes g1; out ffb bf16 (relu)
__global__ __launch_bounds__(256, 2) void k_ff1(
    const float* __restrict__ g0, const float* __restrict__ pend,
    const float* __restrict__ lng, const float* __restrict__ lnb,
    float* __restrict__ g1, const ushort* __restrict__ wst,
    const float* __restrict__ bias, ushort* __restrict__ ffbo) {
  __shared__ __align__(16) ushort hb[5120];
  const int tid = threadIdx.x, lane = tid & 63, wv = tid >> 6;
  const int b = blockIdx.x >> 3, slice = blockIdx.x & 7;
  const int col = lane & 15, kg = lane >> 4;
  stage_ln(g0 + b * 5120, pend + b * 5120, lng, lnb, hb,
           (slice == 0) ? (g1 + b * 5120) : nullptr, nullptr, tid);
  const int t0 = slice * 8 + wv * 2;
  float bv0 = bias[t0 * 16 + col], bv1 = bias[(t0 + 1) * 16 + col];
  __syncthreads();
  asm volatile("s_waitcnt vmcnt(0)" ::: "memory");
  f32x4 acc[2][2];
  acc[0][0] = {bv0, bv0, bv0, bv0}; acc[0][1] = {bv0, bv0, bv0, bv0};
  acc[1][0] = {bv1, bv1, bv1, bv1}; acc[1][1] = {bv1, bv1, bv1, bv1};
  ring_gemm<2, 2, 8>(hb, 256, wst + t0 * 4096 + lane * 8, lane, acc);
  ushort* ob = ffbo + b * 20480;
#pragma unroll
  for (int i = 0; i < 2; ++i) {
    const int og = (t0 + i) * 16 + col;
#pragma unroll
    for (int mt = 0; mt < 2; ++mt)
#pragma unroll
      for (int j = 0; j < 4; ++j) {
        int row = mt * 16 + kg * 4 + j;
        if (row < 20) ob[row * 1024 + og] = f2bf(fmaxf(acc[i][mt][j], 0.f));
      }
  }
}

__global__ __launch_bounds__(256, 2) void k_ff2(const ushort* __restrict__ ffbo,
                                                const ushort* __restrict__ wst,
                                                const float* __restrict__ bias,
                                                float* __restrict__ pend) {
  __shared__ __align__(16) ushort hb[20480];
  const int tid = threadIdx.x, lane = tid & 63, wv = tid >> 6;
  const int b = blockIdx.x >> 2, slice = blockIdx.x & 3;
  const int col = lane & 15, kg = lane >> 4;
  stage_b16(ffbo + b * 20480, hb, 20480, 10, tid);
  const int tile = slice * 4 + wv, og = tile * 16 + col;
  float bv = bias[og];
  __syncthreads();
  asm volatile("s_waitcnt vmcnt(0)" ::: "memory");
  f32x4 acc[1][2];
  acc[0][0] = {bv, bv, bv, bv}; acc[0][1] = {bv, bv, bv, bv};
  ring_gemm<8, 1, 10>(hb, 1024, wst + tile * 16384 + lane * 8, lane, acc);
  float* ob = pend + b * 5120;
#pragma unroll
  for (int mt = 0; mt < 2; ++mt)
#pragma unroll
    for (int j = 0; j < 4; ++j) {
      int row = mt * 16 + kg * 4 + j;
      if (row < 20) ob[row * 256 + og] = acc[0][mt][j];
    }
}

__global__ __launch_bounds__(256) void k_fc(
    const float* __restrict__ g1, const float* __restrict__ pend,
    const float* __restrict__ lng, const float* __restrict__ lnb,
    const float* __restrict__ fcw, const float* __restrict__ fcb,
    float* __restrict__ out) {
  __shared__ float hn[256];
  const int tid = threadIdx.x, b = blockIdx.x;
  if (tid < 64) {
    const int d0 = tid * 4;
    float4 a = *(const float4*)(g1 + b * 5120 + 19 * 256 + d0);
    float4 p = *(const float4*)(pend + b * 5120 + 19 * 256 + d0);
    a.x += p.x; a.y += p.y; a.z += p.z; a.w += p.w;
    float m = wsum(a.x + a.y + a.z + a.w) * (1.f / 256.f);
    float c0 = a.x - m, c1 = a.y - m, c2 = a.z - m, c3 = a.w - m;
    float var = wsum(c0 * c0 + c1 * c1 + c2 * c2 + c3 * c3) * (1.f / 256.f);
    float inv = rsqrtf(var + 1e-5f);
    hn[d0] = c0 * inv * lng[d0] + lnb[d0];
    hn[d0 + 1] = c1 * inv * lng[d0 + 1] + lnb[d0 + 1];
    hn[d0 + 2] = c2 * inv * lng[d0 + 2] + lnb[d0 + 2];
    hn[d0 + 3] = c3 * inv * lng[d0 + 3] + lnb[d0 + 3];
  }
  __syncthreads();
  const int g = tid >> 4, t = tid & 15;
  float s = 0.f;
#pragma unroll
  for (int j = 0; j < 16; ++j) {
    int k = t * 16 + j;
    s += hn[k] * fcw[g * 256 + k];
  }
#pragma unroll
  for (int off = 1; off < 16; off <<= 1) s += __shfl_xor(s, off, 64);
  if (t == 0) out[b * 16 + g] = s + fcb[g];
}

extern "C" void kernel_launch(void* const* d_in, const int* in_sizes, int n_in,
                              void* d_out, int out_size, void* d_ws, size_t ws_size,
                              hipStream_t stream) {
  const float* x    = (const float*)d_in[0];
  const float* c1w  = (const float*)d_in[1];
  const float* c1b  = (const float*)d_in[2];
  const float* c2w  = (const float*)d_in[3];
  const float* c2b  = (const float*)d_in[4];
  const float* lnfg = (const float*)d_in[5];
  const float* lnfb = (const float*)d_in[6];
  const float* tw   = (const float*)d_in[7];
  const float* tb   = (const float*)d_in[8];
  const float* sw   = (const float*)d_in[9];
  const float* sb   = (const float*)d_in[10];
  const float* aiw  = (const float*)d_in[11];
  const float* aib  = (const float*)d_in[12];
  const float* aow  = (const float*)d_in[13];
  const float* aobb = (const float*)d_in[14];
  const float* l1g  = (const float*)d_in[15];
  const float* l1b  = (const float*)d_in[16];
  const float* f1w  = (const float*)d_in[17];
  const float* f1b  = (const float*)d_in[18];
  const float* f2w  = (const float*)d_in[19];
  const float* f2b  = (const float*)d_in[20];
  const float* l2g  = (const float*)d_in[21];
  const float* l2b  = (const float*)d_in[22];
  const float* fcw  = (const float*)d_in[23];
  const float* fcb  = (const float*)d_in[24];
  float* out = (float*)d_out;
  ushort* ws = (ushort*)d_ws;

  ushort* c1g  = ws + O_C1G;
  float* c2o   = (float*)(ws + O_C2O);
  float* g0    = (float*)(ws + O_G0);
  float* g1    = (float*)(ws + O_G1);
  float* pend  = (float*)(ws + O_PEND);
  ushort* qkvo = ws + O_QKV;
  ushort* ffbo = ws + O_FFB;

  k_cvt<<<4096, 256, 0, stream>>>(c2w, tw, sw, aiw, aow, f1w, f2w, ws);
  k_conv1<<<32, 256, 0, stream>>>(x, c1w, c1b, c1g);
  k_conv2<<<128, 256, 0, stream>>>(c1g, ws + S_CONV2, c2b, c2o);
  k_tresea<<<128, 256, 0, stream>>>(c2o, ws + S_TREND, ws + S_SEASON, lnfg,
                                    lnfb, tb, sb, g0);
  for (int l = 0; l < 4; ++l) {
    k_qkv<<<384, 256, 0, stream>>>(
        l == 0 ? g0 : g1, pend, l ? l2g + (l - 1) * 256 : nullptr,
        l ? l2b + (l - 1) * 256 : nullptr, l ? 1 : 0, g0,
        ws + S_QKV + l * 196608, aib + l * 768, qkvo);
    k_attnaow<<<128, 256, 0, stream>>>(qkvo, ws + S_AOW + l * 65536,
                                       aobb + l * 256, pend);
    k_ff1<<<256, 256, 0, stream>>>(g0, pend, l1g + l * 256, l1b + l * 256, g1,
                                   ws + S_F1 + l * 262144, f1b + l * 1024,
                                   ffbo);
    k_ff2<<<128, 256, 0, stream>>>(ffbo, ws + S_F2 + l * 262144, f2b + l * 256,
                                   pend);
  }
  k_fc<<<32, 256, 0, stream>>>(g1, pend, l2g + 3 * 256, l2b + 3 * 256, fcw,
                               fcb, out);
}

// Round 13
// 149.338 us; speedup vs baseline: 1.5247x; 1.0364x over previous
//
#include <hip/hip_runtime.h>
#include <math.h>

typedef __attribute__((ext_vector_type(8))) short short8;
typedef __attribute__((ext_vector_type(4))) short short4v;
typedef __attribute__((ext_vector_type(4))) float f32x4;
typedef unsigned short ushort;
typedef unsigned int uint;
typedef unsigned long long u64;

#define MFMA16(a, b, c) __builtin_amdgcn_mfma_f32_16x16x32_bf16(a, b, c, 0, 0, 0)

__device__ __forceinline__ ushort f2bf(float f) {
  uint u = __float_as_uint(f);
  u = (u + 0x7FFFu + ((u >> 16) & 1u)) >> 16;
  return (ushort)u;
}
__device__ __forceinline__ int swz(int idx, int sh) {
  return idx ^ (((idx >> sh) & 7) << 3);
}
__device__ __forceinline__ float wsum(float v) {
#pragma unroll
  for (int off = 32; off > 0; off >>= 1) v += __shfl_xor(v, off, 64);
  return v;
}
__device__ __forceinline__ void gload16(short8& dst, const ushort* g) {
  u64 ga = (u64)g;
  asm volatile("global_load_dwordx4 %0, %1, off" : "=v"(dst) : "v"(ga));
}
__device__ __forceinline__ void vmw(int n) {
  if (n >= 7) asm volatile("s_waitcnt vmcnt(7)" ::: "memory");
  else if (n == 6) asm volatile("s_waitcnt vmcnt(6)" ::: "memory");
  else if (n == 5) asm volatile("s_waitcnt vmcnt(5)" ::: "memory");
  else if (n == 4) asm volatile("s_waitcnt vmcnt(4)" ::: "memory");
  else if (n == 3) asm volatile("s_waitcnt vmcnt(3)" ::: "memory");
  else if (n == 2) asm volatile("s_waitcnt vmcnt(2)" ::: "memory");
  else if (n == 1) asm volatile("s_waitcnt vmcnt(1)" ::: "memory");
  else asm volatile("s_waitcnt vmcnt(0)" ::: "memory");
}

// ---- weight stream layout (tile-major): chunk(1KB) = (tile, kc, ks) ------
#define S_CONV2 0
#define S_TREND 196608
#define S_SEASON 262144
#define S_QKV 327680
#define S_AOW 1114112
#define S_F1 1376256
#define S_F2 2424832
#define WTOT 3473408
// activation buffers (ushort offsets in d_ws)
#define O_C2O 3653632   // f32 [32][5120]
#define O_G0 3981312    // f32 [32][5120]
#define O_G1 4308992    // f32 [32][5120]
#define O_PEND 4636672  // f32 [32][5120]
#define O_QKV 4964352   // bf16 [32][15360]
#define O_FFB 5455872   // bf16 [32][20480]

template <int NCH>
__device__ __forceinline__ void dec2(int idx, int& row, int& k) {
  int pos = idx & 511, lane = pos >> 3, j = pos & 7;
  int kg = lane >> 4, col = lane & 15;
  int chunk = idx >> 9;
  int tile = chunk / (NCH * 4), r = chunk - tile * (NCH * 4);
  int kc = r >> 2, ks = r & 3;
  row = tile * 16 + col;
  k = kc * 128 + ks * 32 + kg * 8 + j;
}

__global__ void k_cvt(const float* __restrict__ c2w, const float* __restrict__ tw,
                      const float* __restrict__ sw, const float* __restrict__ aiw,
                      const float* __restrict__ aow, const float* __restrict__ f1w,
                      const float* __restrict__ f2w, ushort* __restrict__ ws) {
  for (int i = blockIdx.x * blockDim.x + threadIdx.x; i < WTOT;
       i += gridDim.x * blockDim.x) {
    float v; int row, k;
    if (i < S_TREND) {
      dec2<6>(i, row, k);
      int t = k >> 8, e = k & 255;
      v = c2w[row * 768 + e * 3 + t];
    } else if (i < S_SEASON) { dec2<2>(i - S_TREND, row, k); v = tw[row * 256 + k]; }
    else if (i < S_QKV) { dec2<2>(i - S_SEASON, row, k); v = sw[row * 256 + k]; }
    else if (i < S_AOW) {
      int r = i - S_QKV; int l = r / 196608; r -= l * 196608;
      dec2<2>(r, row, k); v = aiw[(size_t)l * 196608 + row * 256 + k];
    } else if (i < S_F1) {
      int r = i - S_AOW; int l = r >> 16; r &= 65535;
      dec2<2>(r, row, k); v = aow[l * 65536 + row * 256 + k];
    } else if (i < S_F2) {
      int r = i - S_F1; int l = r >> 18; r &= 262143;
      dec2<2>(r, row, k); v = f1w[l * 262144 + row * 256 + k];
    } else {
      int r = i - S_F2; int l = r >> 18; r &= 262143;
      dec2<8>(r, row, k); v = f2w[l * 262144 + row * 1024 + k];
    }
    ws[i] = f2bf(v);
  }
}

// ---- generic ring GEMM core: wave streams MY consecutive tiles ----------
template <int NCH, int MY, int ASH>
__device__ __forceinline__ void ring_gemm(const ushort* __restrict__ A, int lda,
                                          const ushort* __restrict__ ws0,
                                          int lane, f32x4 (&acc)[MY][2]) {
  constexpr int C = MY * NCH * 4;
  constexpr int R = (C < 8) ? C : 8;
  const int col = lane & 15, kg = lane >> 4;
  const int r1c = (16 + col > 19) ? 19 : (16 + col);
  short8 rg[R];
#pragma unroll
  for (int r = 0; r < R; ++r) gload16(rg[r], ws0 + r * 512);
  short8 af0[4], af1[4];
#pragma unroll
  for (int c = 0; c < C; ++c) {
    const int i = c / (NCH * 4), r = c - i * (NCH * 4);
    const int kc = r >> 2, ks = r & 3;
    if (ks == 0) {
#pragma unroll
      for (int s = 0; s < 4; ++s) {
        const int k0 = kc * 128 + s * 32 + kg * 8;
        af0[s] = *(const short8*)(A + swz(col * lda + k0, ASH));
        af1[s] = *(const short8*)(A + swz(r1c * lda + k0, ASH));
      }
    }
    int allow = C - 1 - c; if (allow > R - 1) allow = R - 1;
    vmw(allow);
    __builtin_amdgcn_sched_barrier(0);
    acc[i][0] = MFMA16(af0[ks], rg[c % R], acc[i][0]);
    acc[i][1] = MFMA16(af1[ks], rg[c % R], acc[i][1]);
    if (c + R < C) gload16(rg[c % R], ws0 + (c + R) * 512);
  }
}

// ---- A staging helpers (256 threads) ------------------------------------
__device__ __forceinline__ void stage_b16(const ushort* __restrict__ g, ushort* hb,
                                          int n, int sh, int tid) {
  for (int i = tid * 8; i < n; i += 2048) {
    short8 v = *(const short8*)(g + i);
    *(short8*)(hb + swz(i, sh)) = v;
  }
}
__device__ __forceinline__ void stage_f32(const float* __restrict__ g, ushort* hb, int tid) {
  for (int i = tid * 8; i < 5120; i += 2048) {
    float4 a = *(const float4*)(g + i);
    float4 b = *(const float4*)(g + i + 4);
    short8 t;
    t[0] = f2bf(a.x); t[1] = f2bf(a.y); t[2] = f2bf(a.z); t[3] = f2bf(a.w);
    t[4] = f2bf(b.x); t[5] = f2bf(b.y); t[6] = f2bf(b.z); t[7] = f2bf(b.w);
    *(short8*)(hb + swz(i, 8)) = t;
  }
}
// LN(g1 [+pend]) -> hb bf16 swz8 ; optional fp32 writeback gout / LDS copy
__device__ __forceinline__ void stage_ln(const float* __restrict__ g1,
                                         const float* __restrict__ pend,
                                         const float* __restrict__ gam,
                                         const float* __restrict__ bet,
                                         ushort* hb, float* __restrict__ gout,
                                         float* f32lds, int tid) {
  const int lane = tid & 63, w = tid >> 6, d0 = lane * 4;
  for (int r = w; r < 20; r += 4) {
    float4 a = *(const float4*)(g1 + r * 256 + d0);
    if (pend) {
      float4 p = *(const float4*)(pend + r * 256 + d0);
      a.x += p.x; a.y += p.y; a.z += p.z; a.w += p.w;
    }
    float m = wsum(a.x + a.y + a.z + a.w) * (1.f / 256.f);
    float c0 = a.x - m, c1 = a.y - m, c2 = a.z - m, c3 = a.w - m;
    float var = wsum(c0 * c0 + c1 * c1 + c2 * c2 + c3 * c3) * (1.f / 256.f);
    float inv = rsqrtf(var + 1e-5f);
    float o0 = c0 * inv * gam[d0] + bet[d0];
    float o1 = c1 * inv * gam[d0 + 1] + bet[d0 + 1];
    float o2 = c2 * inv * gam[d0 + 2] + bet[d0 + 2];
    float o3 = c3 * inv * gam[d0 + 3] + bet[d0 + 3];
    short4v t; t[0] = f2bf(o0); t[1] = f2bf(o1); t[2] = f2bf(o2); t[3] = f2bf(o3);
    *(short4v*)(hb + swz(r * 256 + d0, 8)) = t;
    if (gout) { float4 o = {o0, o1, o2, o3}; *(float4*)(gout + r * 256 + d0) = o; }
    if (f32lds) { float4 o = {o0, o1, o2, o3}; *(float4*)(f32lds + r * 256 + d0) = o; }
  }
}

// ---- phase kernels -------------------------------------------------------
// conv1 fused into conv2: each block recomputes conv1 (cheap) in LDS.
__global__ __launch_bounds__(256, 2) void k_conv12(
    const float* __restrict__ x, const float* __restrict__ c1w,
    const float* __restrict__ c1b, const ushort* __restrict__ wst,
    const float* __restrict__ c2b, float* __restrict__ c2o) {
  __shared__ float xs[24][16];
  __shared__ __align__(16) ushort c1u[5632];
  const int tid = threadIdx.x, lane = tid & 63, wv = tid >> 6;
  const int b = blockIdx.x >> 2, slice = blockIdx.x & 3;
  const int col = lane & 15, kg = lane >> 4;
  for (int i = tid; i < 24 * 16; i += 256) {
    int r = i >> 4, c = i & 15;
    xs[r][c] = (r < 23) ? x[((size_t)b * 4000 + 3977 + r) * 16 + c] : 0.f;
  }
  __syncthreads();
  {
    const int d = tid;
    const float* wr = c1w + d * 48;
    float acc[21];
    const float bv = c1b[d];
#pragma unroll
    for (int r = 0; r < 21; ++r) acc[r] = bv;
    for (int c = 0; c < 16; ++c) {
      float xv[23];
#pragma unroll
      for (int i = 0; i < 23; ++i) xv[i] = xs[i + 1][c];
      float w0 = wr[c * 3], w1 = wr[c * 3 + 1], w2 = wr[c * 3 + 2];
#pragma unroll
      for (int r = 0; r < 21; ++r)
        acc[r] += xv[r] * w0 + xv[r + 1] * w1 + xv[r + 2] * w2;
    }
#pragma unroll
    for (int r = 0; r < 21; ++r)
      c1u[swz(r * 256 + d, 8)] = f2bf(fmaxf(acc[r], 0.f));
    c1u[swz(21 * 256 + d, 8)] = 0;
  }
  const int tile = slice * 4 + wv, og = tile * 16 + col;
  float bv2 = c2b[og];
  __syncthreads();
  asm volatile("s_waitcnt vmcnt(0)" ::: "memory");
  f32x4 acc2[1][2];
  acc2[0][0] = {bv2, bv2, bv2, bv2}; acc2[0][1] = {bv2, bv2, bv2, bv2};
  ring_gemm<6, 1, 8>(c1u, 256, wst + tile * 12288 + lane * 8, lane, acc2);
  float* ob = c2o + b * 5120;
#pragma unroll
  for (int mt = 0; mt < 2; ++mt)
#pragma unroll
    for (int j = 0; j < 4; ++j) {
      int row = mt * 16 + kg * 4 + j;
      if (row < 20) ob[row * 256 + og] = fmaxf(acc2[0][mt][j], 0.f);
    }
}

__global__ __launch_bounds__(256, 2) void k_tresea(
    const float* __restrict__ c2o, const ushort* __restrict__ wtr,
    const ushort* __restrict__ wse, const float* __restrict__ lnfg,
    const float* __restrict__ lnfb, const float* __restrict__ tb,
    const float* __restrict__ sb, float* __restrict__ g0) {
  __shared__ __align__(16) ushort hb[5120];
  __shared__ float hf[5120];
  const int tid = threadIdx.x, lane = tid & 63, wv = tid >> 6;
  const int b = blockIdx.x >> 2, slice = blockIdx.x & 3;
  const int col = lane & 15, kg = lane >> 4;
  stage_ln(c2o + b * 5120, nullptr, lnfg, lnfb, hb, nullptr, hf, tid);
  const int tile = slice * 4 + wv, og = tile * 16 + col;
  float bt = tb[og], bs = sb[og];
  __syncthreads();
  asm volatile("s_waitcnt vmcnt(0)" ::: "memory");
  f32x4 at[1][2], as_[1][2];
  at[0][0] = {bt, bt, bt, bt}; at[0][1] = {bt, bt, bt, bt};
  as_[0][0] = {bs, bs, bs, bs}; as_[0][1] = {bs, bs, bs, bs};
  ring_gemm<2, 1, 8>(hb, 256, wtr + tile * 4096 + lane * 8, lane, at);
  ring_gemm<2, 1, 8>(hb, 256, wse + tile * 4096 + lane * 8, lane, as_);
  float* ob = g0 + b * 5120;
#pragma unroll
  for (int mt = 0; mt < 2; ++mt)
#pragma unroll
    for (int j = 0; j < 4; ++j) {
      int row = mt * 16 + kg * 4 + j;
      if (row < 20)
        ob[row * 256 + og] = hf[row * 256 + og] + at[0][mt][j] + sinf(as_[0][mt][j]);
    }
}

// qkv projection; fuse_ln: A = LN2(g_in + pend) (slice0 writes gout fp32)
__global__ __launch_bounds__(256, 2) void k_qkv(
    const float* __restrict__ gin, const float* __restrict__ pend,
    const float* __restrict__ lng, const float* __restrict__ lnb, int fuse_ln,
    float* __restrict__ gout, const ushort* __restrict__ wst,
    const float* __restrict__ bias, ushort* __restrict__ qkvo) {
  __shared__ __align__(16) ushort hb[5120];
  const int tid = threadIdx.x, lane = tid & 63, wv = tid >> 6;
  const int b = blockIdx.x / 12, slice = blockIdx.x % 12;
  const int col = lane & 15, kg = lane >> 4;
  if (fuse_ln)
    stage_ln(gin + b * 5120, pend + b * 5120, lng, lnb, hb,
             (slice == 0) ? (gout + b * 5120) : nullptr, nullptr, tid);
  else
    stage_f32(gin + b * 5120, hb, tid);
  const int tile = slice * 4 + wv, og = tile * 16 + col;
  float bv = bias[og];
  __syncthreads();
  asm volatile("s_waitcnt vmcnt(0)" ::: "memory");
  f32x4 acc[1][2];
  acc[0][0] = {bv, bv, bv, bv}; acc[0][1] = {bv, bv, bv, bv};
  ring_gemm<2, 1, 8>(hb, 256, wst + tile * 4096 + lane * 8, lane, acc);
  ushort* ob = qkvo + b * 15360;
#pragma unroll
  for (int mt = 0; mt < 2; ++mt)
#pragma unroll
    for (int j = 0; j < 4; ++j) {
      int row = mt * 16 + kg * 4 + j;
      if (row < 20) ob[row * 768 + og] = f2bf(acc[0][mt][j]);
    }
}

// fused: attention (redundant per slice) + FULL out-proj + LN1 + ff1 slice
__global__ __launch_bounds__(256, 1) void k_aff1(
    const ushort* __restrict__ qkvo, const ushort* __restrict__ waow,
    const float* __restrict__ aobb, const float* __restrict__ g0,
    const float* __restrict__ l1g, const float* __restrict__ l1b,
    float* __restrict__ g1, const ushort* __restrict__ wf1,
    const float* __restrict__ f1b, ushort* __restrict__ ffbo) {
  __shared__ __align__(16) ushort qb[15360];  // proj f32 overlays after QK^T
  __shared__ __align__(16) ushort vT[8192];
  __shared__ __align__(16) ushort Pb[5120];
  __shared__ __align__(16) ushort aob[5120];
  __shared__ float sc[3200];
  __shared__ __align__(16) ushort hb[5120];
  float* proj = (float*)qb;  // 20480B <= 30720B, qb dead after QK^T
  const int tid = threadIdx.x, lane = tid & 63, wv = tid >> 6;
  const int b = blockIdx.x >> 3, slice = blockIdx.x & 7;
  const int col = lane & 15, kg = lane >> 4;
  const int r1c = (16 + col > 19) ? 19 : (16 + col);

  stage_b16(qkvo + b * 15360, qb, 15360, 8, tid);
  __syncthreads();
  for (int i = tid; i < 8192; i += 256) {
    int hh = i >> 10, rem = i & 1023, dh = rem >> 5, tk = rem & 31;
    ushort v = (tk < 20) ? qb[swz(tk * 768 + 512 + hh * 32 + dh, 8)] : (ushort)0;
    vT[swz(i, 5)] = v;
  }
  __syncthreads();
  for (int hh = wv; hh < 8; hh += 4) {
    short8 aq[2], bk[2];
    aq[0] = *(const short8*)(qb + swz(col * 768 + hh * 32 + kg * 8, 8));
    aq[1] = *(const short8*)(qb + swz(r1c * 768 + hh * 32 + kg * 8, 8));
    bk[0] = *(const short8*)(qb + swz(col * 768 + 256 + hh * 32 + kg * 8, 8));
    bk[1] = *(const short8*)(qb + swz(r1c * 768 + 256 + hh * 32 + kg * 8, 8));
    f32x4 d[2][2];
#pragma unroll
    for (int mt = 0; mt < 2; ++mt)
#pragma unroll
      for (int nt = 0; nt < 2; ++nt) {
        d[mt][nt] = {0.f, 0.f, 0.f, 0.f};
        d[mt][nt] = MFMA16(aq[mt], bk[nt], d[mt][nt]);
      }
#pragma unroll
    for (int mt = 0; mt < 2; ++mt)
#pragma unroll
      for (int nt = 0; nt < 2; ++nt)
#pragma unroll
        for (int j = 0; j < 4; ++j) {
          int row = mt * 16 + kg * 4 + j, kj = nt * 16 + col;
          if (row < 20 && kj < 20)
            sc[hh * 400 + row * 20 + kj] = d[mt][nt][j] * 0.17677669529663687f;
        }
  }
  __syncthreads();
  if (tid < 160) {
    const int hh = tid / 20, q = tid - hh * 20;
    const float* row = sc + hh * 400 + q * 20;
    float m = row[0];
#pragma unroll
    for (int j = 1; j < 20; ++j) m = fmaxf(m, row[j]);
    float e[20], s = 0.f;
#pragma unroll
    for (int j = 0; j < 20; ++j) { e[j] = __expf(row[j] - m); s += e[j]; }
    float inv = 1.f / s;
#pragma unroll
    for (int j = 0; j < 20; ++j) Pb[swz(hh * 640 + q * 32 + j, 5)] = f2bf(e[j] * inv);
#pragma unroll
    for (int j = 20; j < 32; ++j) Pb[swz(hh * 640 + q * 32 + j, 5)] = 0;
  }
  __syncthreads();
  for (int hh = wv; hh < 8; hh += 4) {
    short8 ap[2], bvv[2];
    ap[0] = *(const short8*)(Pb + swz(hh * 640 + col * 32 + kg * 8, 5));
    ap[1] = *(const short8*)(Pb + swz(hh * 640 + r1c * 32 + kg * 8, 5));
    bvv[0] = *(const short8*)(vT + swz(hh * 1024 + col * 32 + kg * 8, 5));
    bvv[1] = *(const short8*)(vT + swz(hh * 1024 + (16 + col) * 32 + kg * 8, 5));
    f32x4 d[2][2];
#pragma unroll
    for (int mt = 0; mt < 2; ++mt)
#pragma unroll
      for (int nt = 0; nt < 2; ++nt) {
        d[mt][nt] = {0.f, 0.f, 0.f, 0.f};
        d[mt][nt] = MFMA16(ap[mt], bvv[nt], d[mt][nt]);
      }
#pragma unroll
    for (int mt = 0; mt < 2; ++mt)
#pragma unroll
      for (int nt = 0; nt < 2; ++nt)
#pragma unroll
        for (int j = 0; j < 4; ++j) {
          int row = mt * 16 + kg * 4 + j, dc = nt * 16 + col;
          if (row < 20) aob[swz(row * 256 + hh * 32 + dc, 8)] = f2bf(d[mt][nt][j]);
        }
  }
  __syncthreads();

  // FULL out-projection: wave wv computes tiles wv*4 .. wv*4+3 -> proj f32
  {
    float bo[4];
#pragma unroll
    for (int i = 0; i < 4; ++i) bo[i] = aobb[(wv * 4 + i) * 16 + col];
    asm volatile("s_waitcnt vmcnt(0)" ::: "memory");
    f32x4 acc[4][2];
#pragma unroll
    for (int i = 0; i < 4; ++i) {
      acc[i][0] = {bo[i], bo[i], bo[i], bo[i]};
      acc[i][1] = {bo[i], bo[i], bo[i], bo[i]};
    }
    ring_gemm<2, 4, 8>(aob, 256, waow + (wv * 4) * 4096 + lane * 8, lane, acc);
#pragma unroll
    for (int i = 0; i < 4; ++i) {
      const int og = (wv * 4 + i) * 16 + col;
#pragma unroll
      for (int mt = 0; mt < 2; ++mt)
#pragma unroll
        for (int j = 0; j < 4; ++j) {
          int row = mt * 16 + kg * 4 + j;
          if (row < 20) proj[row * 256 + og] = acc[i][mt][j];
        }
    }
  }
  __syncthreads();

  // LN1(g0 + proj) -> hb bf16 (slice0 writes g1 fp32)
  {
    const int d0 = lane * 4;
    for (int r = wv; r < 20; r += 4) {
      float4 a = *(const float4*)(g0 + b * 5120 + r * 256 + d0);
      a.x += proj[r * 256 + d0];
      a.y += proj[r * 256 + d0 + 1];
      a.z += proj[r * 256 + d0 + 2];
      a.w += proj[r * 256 + d0 + 3];
      float m = wsum(a.x + a.y + a.z + a.w) * (1.f / 256.f);
      float c0 = a.x - m, c1 = a.y - m, c2 = a.z - m, c3 = a.w - m;
      float var = wsum(c0 * c0 + c1 * c1 + c2 * c2 + c3 * c3) * (1.f / 256.f);
      float inv = rsqrtf(var + 1e-5f);
      float o0 = c0 * inv * l1g[d0] + l1b[d0];
      float o1 = c1 * inv * l1g[d0 + 1] + l1b[d0 + 1];
      float o2 = c2 * inv * l1g[d0 + 2] + l1b[d0 + 2];
      float o3 = c3 * inv * l1g[d0 + 3] + l1b[d0 + 3];
      short4v t; t[0] = f2bf(o0); t[1] = f2bf(o1); t[2] = f2bf(o2); t[3] = f2bf(o3);
      *(short4v*)(hb + swz(r * 256 + d0, 8)) = t;
      if (slice == 0) {
        float4 o = {o0, o1, o2, o3};
        *(float4*)(g1 + b * 5120 + r * 256 + d0) = o;
      }
    }
  }
  __syncthreads();

  // ff1 slice: wave does tiles t0 = slice*8 + wv*2, +1 (relu, bf16 out)
  {
    const int t0 = slice * 8 + wv * 2;
    float bf0 = f1b[t0 * 16 + col], bf1 = f1b[(t0 + 1) * 16 + col];
    asm volatile("s_waitcnt vmcnt(0)" ::: "memory");
    f32x4 acc[2][2];
    acc[0][0] = {bf0, bf0, bf0, bf0}; acc[0][1] = {bf0, bf0, bf0, bf0};
    acc[1][0] = {bf1, bf1, bf1, bf1}; acc[1][1] = {bf1, bf1, bf1, bf1};
    ring_gemm<2, 2, 8>(hb, 256, wf1 + t0 * 4096 + lane * 8, lane, acc);
    ushort* ob = ffbo + b * 20480;
#pragma unroll
    for (int i = 0; i < 2; ++i) {
      const int og = (t0 + i) * 16 + col;
#pragma unroll
      for (int mt = 0; mt < 2; ++mt)
#pragma unroll
        for (int j = 0; j < 4; ++j) {
          int row = mt * 16 + kg * 4 + j;
          if (row < 20) ob[row * 1024 + og] = f2bf(fmaxf(acc[i][mt][j], 0.f));
        }
    }
  }
}

__global__ __launch_bounds__(256, 2) void k_ff2(const ushort* __restrict__ ffbo,
                                                const ushort* __restrict__ wst,
                                                const float* __restrict__ bias,
                                                float* __restrict__ pend) {
  __shared__ __align__(16) ushort hb[20480];
  const int tid = threadIdx.x, lane = tid & 63, wv = tid >> 6;
  const int b = blockIdx.x >> 2, slice = blockIdx.x & 3;
  const int col = lane & 15, kg = lane >> 4;
  stage_b16(ffbo + b * 20480, hb, 20480, 10, tid);
  const int tile = slice * 4 + wv, og = tile * 16 + col;
  float bv = bias[og];
  __syncthreads();
  asm volatile("s_waitcnt vmcnt(0)" ::: "memory");
  f32x4 acc[1][2];
  acc[0][0] = {bv, bv, bv, bv}; acc[0][1] = {bv, bv, bv, bv};
  ring_gemm<8, 1, 10>(hb, 1024, wst + tile * 16384 + lane * 8, lane, acc);
  float* ob = pend + b * 5120;
#pragma unroll
  for (int mt = 0; mt < 2; ++mt)
#pragma unroll
    for (int j = 0; j < 4; ++j) {
      int row = mt * 16 + kg * 4 + j;
      if (row < 20) ob[row * 256 + og] = acc[0][mt][j];
    }
}

__global__ __launch_bounds__(256) void k_fc(
    const float* __restrict__ g1, const float* __restrict__ pend,
    const float* __restrict__ lng, const float* __restrict__ lnb,
    const float* __restrict__ fcw, const float* __restrict__ fcb,
    float* __restrict__ out) {
  __shared__ float hn[256];
  const int tid = threadIdx.x, b = blockIdx.x;
  if (tid < 64) {
    const int d0 = tid * 4;
    float4 a = *(const float4*)(g1 + b * 5120 + 19 * 256 + d0);
    float4 p = *(const float4*)(pend + b * 5120 + 19 * 256 + d0);
    a.x += p.x; a.y += p.y; a.z += p.z; a.w += p.w;
    float m = wsum(a.x + a.y + a.z + a.w) * (1.f / 256.f);
    float c0 = a.x - m, c1 = a.y - m, c2 = a.z - m, c3 = a.w - m;
    float var = wsum(c0 * c0 + c1 * c1 + c2 * c2 + c3 * c3) * (1.f / 256.f);
    float inv = rsqrtf(var + 1e-5f);
    hn[d0] = c0 * inv * lng[d0] + lnb[d0];
    hn[d0 + 1] = c1 * inv * lng[d0 + 1] + lnb[d0 + 1];
    hn[d0 + 2] = c2 * inv * lng[d0 + 2] + lnb[d0 + 2];
    hn[d0 + 3] = c3 * inv * lng[d0 + 3] + lnb[d0 + 3];
  }
  __syncthreads();
  const int g = tid >> 4, t = tid & 15;
  float s = 0.f;
#pragma unroll
  for (int j = 0; j < 16; ++j) {
    int k = t * 16 + j;
    s += hn[k] * fcw[g * 256 + k];
  }
#pragma unroll
  for (int off = 1; off < 16; off <<= 1) s += __shfl_xor(s, off, 64);
  if (t == 0) out[b * 16 + g] = s + fcb[g];
}

extern "C" void kernel_launch(void* const* d_in, const int* in_sizes, int n_in,
                              void* d_out, int out_size, void* d_ws, size_t ws_size,
                              hipStream_t stream) {
  const float* x    = (const float*)d_in[0];
  const float* c1w  = (const float*)d_in[1];
  const float* c1b  = (const float*)d_in[2];
  const float* c2w  = (const float*)d_in[3];
  const float* c2b  = (const float*)d_in[4];
  const float* lnfg = (const float*)d_in[5];
  const float* lnfb = (const float*)d_in[6];
  const float* tw   = (const float*)d_in[7];
  const float* tb   = (const float*)d_in[8];
  const float* sw   = (const float*)d_in[9];
  const float* sb   = (const float*)d_in[10];
  const float* aiw  = (const float*)d_in[11];
  const float* aib  = (const float*)d_in[12];
  const float* aow  = (const float*)d_in[13];
  const float* aobb = (const float*)d_in[14];
  const float* l1g  = (const float*)d_in[15];
  const float* l1b  = (const float*)d_in[16];
  const float* f1w  = (const float*)d_in[17];
  const float* f1b  = (const float*)d_in[18];
  const float* f2w  = (const float*)d_in[19];
  const float* f2b  = (const float*)d_in[20];
  const float* l2g  = (const float*)d_in[21];
  const float* l2b  = (const float*)d_in[22];
  const float* fcw  = (const float*)d_in[23];
  const float* fcb  = (const float*)d_in[24];
  float* out = (float*)d_out;
  ushort* ws = (ushort*)d_ws;

  float* c2o   = (float*)(ws + O_C2O);
  float* g0    = (float*)(ws + O_G0);
  float* g1    = (float*)(ws + O_G1);
  float* pend  = (float*)(ws + O_PEND);
  ushort* qkvo = ws + O_QKV;
  ushort* ffbo = ws + O_FFB;

  k_cvt<<<4096, 256, 0, stream>>>(c2w, tw, sw, aiw, aow, f1w, f2w, ws);
  k_conv12<<<128, 256, 0, stream>>>(x, c1w, c1b, ws + S_CONV2, c2b, c2o);
  k_tresea<<<128, 256, 0, stream>>>(c2o, ws + S_TREND, ws + S_SEASON, lnfg,
                                    lnfb, tb, sb, g0);
  for (int l = 0; l < 4; ++l) {
    k_qkv<<<384, 256, 0, stream>>>(
        l == 0 ? g0 : g1, pend, l ? l2g + (l - 1) * 256 : nullptr,
        l ? l2b + (l - 1) * 256 : nullptr, l ? 1 : 0, g0,
        ws + S_QKV + l * 196608, aib + l * 768, qkvo);
    k_aff1<<<256, 256, 0, stream>>>(qkvo, ws + S_AOW + l * 65536,
                                    aobb + l * 256, g0, l1g + l * 256,
                                    l1b + l * 256, g1, ws + S_F1 + l * 262144,
                                    f1b + l * 1024, ffbo);
    k_ff2<<<128, 256, 0, stream>>>(ffbo, ws + S_F2 + l * 262144, f2b + l * 256,
                                   pend);
  }
  k_fc<<<32, 256, 0, stream>>>(g1, pend, l2g + 3 * 256, l2b + 3 * 256, fcw,
                               fcb, out);
}